// Round 6
// baseline (790.006 us; speedup 1.0000x reference)
//
#include <hip/hip_runtime.h>
#include <stdint.h>

// Round 9 (= R8 with the LDS-limit bug fixed):
//  - gemm_mlv's zf staging tile now bf16 ushort[128][132] (33.8 KB) instead of
//    float[128][129] (66 KB > 64 KB static-LDS cap -> launch/compile failure,
//    the R8 container crash). f2b moved to the C-write phase; emit phase is a
//    pure 16B LDS read -> 16B global store. +4 pad => row stride 264B == 2
//    banks mod 32: free 2-way alias on the emit read.
//  - scan1/2/3 collapsed into a single 1024-thread block scan (12 elems/thread
//    + LDS Hillis-Steele over 1024 partials): 3 launches -> 1.
//  - Decoder confirmed write-bound (R4 ablation): 128x256 tile, nt stores,
//    fast sigmoid.
//  - Carried: SpMM-first layer 2, bf16 512B gathers, unrolled 32-edge batches,
//    fused hist+prep, compile-time-K GEMM.

#define NN 12288   // nodes
#define FF 512     // input feature dim
#define HD1 256    // hidden 1
#define HD2 128    // latent
#define EE 393216  // edges  (EE % 256 == 0)

typedef short bf16x8 __attribute__((ext_vector_type(8)));   // 8 bf16 in 4 VGPRs
typedef float f32x16 __attribute__((ext_vector_type(16)));

__device__ inline unsigned short f2b(float f) {
  // fp32 -> bf16 round-to-nearest-even (inputs finite)
  unsigned int u = __float_as_uint(f);
  unsigned int r = u + 0x7fffu + ((u >> 16) & 1u);
  return (unsigned short)(r >> 16);
}

__device__ inline float b2f(unsigned short u) {
  return __uint_as_float((unsigned int)u << 16);
}

__device__ inline bf16x8 ldb8(const unsigned short* p) {
  return *(const bf16x8*)p;
}

// load 8 fp32, convert to bf16 fragment
__device__ inline bf16x8 ldf8(const float* p) {
  float4 v0 = ((const float4*)p)[0];
  float4 v1 = ((const float4*)p)[1];
  bf16x8 r;
  r[0] = (short)f2b(v0.x); r[1] = (short)f2b(v0.y);
  r[2] = (short)f2b(v0.z); r[3] = (short)f2b(v0.w);
  r[4] = (short)f2b(v1.x); r[5] = (short)f2b(v1.y);
  r[6] = (short)f2b(v1.z); r[7] = (short)f2b(v1.w);
  return r;
}

__device__ inline f32x16 mfma32(bf16x8 a, bf16x8 b, f32x16 c) {
  return __builtin_amdgcn_mfma_f32_32x32x16_bf16(a, b, c, 0, 0, 0);
}

__device__ inline float sigmoid_fast(float v) {
  return __builtin_amdgcn_rcpf(1.0f + __expf(-v));   // v_rcp_f32: 1 ulp
}

// ---------------- fused hist + dtype prep ----------------
#define HIST_NB   (EE / 256)
#define PREP_NX   (NN * FF / 4)
#define PREP_NW1  (FF * HD1)
#define PREP_NW23 (HD1 * HD2)

__global__ void k_hist_prep(const int* __restrict__ src, int* __restrict__ deg,
                            const float* __restrict__ x, unsigned short* __restrict__ xb,
                            const float* __restrict__ W1, unsigned short* __restrict__ W1t,
                            const float* __restrict__ W2, const float* __restrict__ W3,
                            unsigned short* __restrict__ W23t) {
  if (blockIdx.x < HIST_NB) {
    int e = blockIdx.x * 256 + threadIdx.x;
    atomicAdd(&deg[src[e]], 1);
    return;
  }
  int gid = (blockIdx.x - HIST_NB) * 256 + threadIdx.x;
  if (gid < PREP_NX) {
    float4 v = ((const float4*)x)[gid];
    ushort4 o;
    o.x = f2b(v.x); o.y = f2b(v.y); o.z = f2b(v.z); o.w = f2b(v.w);
    ((ushort4*)xb)[gid] = o;
    return;
  }
  int idx = gid - PREP_NX;
  if (idx < PREP_NW1) {                       // W1 [FF][HD1] -> W1t [HD1][FF]
    int k = idx / HD1, n = idx - k * HD1;
    W1t[(size_t)n * FF + k] = f2b(W1[idx]);
    return;
  }
  idx -= PREP_NW1;
  if (idx < PREP_NW23) {                      // W2 [HD1][HD2] -> W23t [0:HD2][HD1]
    int k = idx / HD2, n = idx - k * HD2;
    W23t[(size_t)n * HD1 + k] = f2b(W2[idx]);
    return;
  }
  idx -= PREP_NW23;
  if (idx < PREP_NW23) {                      // W3 -> W23t [HD2:2*HD2][HD1]
    int k = idx / HD2, n = idx - k * HD2;
    W23t[(size_t)(HD2 + n) * HD1 + k] = f2b(W3[idx]);
  }
}

// ---------------- CSR build ----------------

// single-block exclusive scan over NN=12288 degrees (1024 thr x 12 elems)
__global__ __launch_bounds__(1024) void k_scan(const int* __restrict__ deg,
                                               int* __restrict__ off,
                                               int* __restrict__ cur) {
  __shared__ int part[1024];
  int t = threadIdx.x;
  int base = t * 12;
  int v[12];
  int s = 0;
#pragma unroll
  for (int j = 0; j < 12; ++j) { v[j] = deg[base + j]; s += v[j]; }
  part[t] = s;
  __syncthreads();
  for (int st = 1; st < 1024; st <<= 1) {
    int u = (t >= st) ? part[t - st] : 0;
    __syncthreads();
    part[t] += u;
    __syncthreads();
  }
  int run = part[t] - s;                 // exclusive prefix of this chunk
#pragma unroll
  for (int j = 0; j < 12; ++j) {
    off[base + j] = run;
    cur[base + j] = run;
    run += v[j];
  }
}

// permute (dst, val) into CSR order -> contiguous metadata for the SpMMs
__global__ void k_fill(const int* __restrict__ src, const int* __restrict__ dst,
                       const float* __restrict__ ev, int* __restrict__ cur,
                       int* __restrict__ dstp, float* __restrict__ valp) {
  int e = blockIdx.x * 256 + threadIdx.x;
  int p = atomicAdd(&cur[src[e]], 1);
  dstp[p] = dst[e];
  valp[p] = ev[e];
}

// ---------------- GEMM: C[M,Nn] = A[M,K] * Bt[Nn,K]^T, bf16 out ----------------

template <int K>
__global__ __launch_bounds__(256) void gemm_btb(
    const unsigned short* __restrict__ A, const unsigned short* __restrict__ Bt,
    unsigned short* __restrict__ C, int Nn) {
  int wave = threadIdx.x >> 6, lane = threadIdx.x & 63;
  int wr = wave >> 1, wc = wave & 1;
  int row0 = blockIdx.x * 128 + wr * 64;
  int col0 = blockIdx.y * 128 + wc * 64;
  int lm = lane & 31, lk = (lane >> 5) * 8;

  f32x16 acc[2][2] = {};
  const unsigned short* a0p = A + (size_t)(row0 + lm) * K + lk;
  const unsigned short* a1p = a0p + (size_t)32 * K;
  const unsigned short* b0p = Bt + (size_t)(col0 + lm) * K + lk;
  const unsigned short* b1p = b0p + (size_t)32 * K;

#pragma unroll 4
  for (int k0 = 0; k0 < K; k0 += 16) {
    bf16x8 a0 = ldb8(a0p + k0), a1 = ldb8(a1p + k0);
    bf16x8 b0 = ldb8(b0p + k0), b1 = ldb8(b1p + k0);
    acc[0][0] = mfma32(a0, b0, acc[0][0]);
    acc[0][1] = mfma32(a0, b1, acc[0][1]);
    acc[1][0] = mfma32(a1, b0, acc[1][0]);
    acc[1][1] = mfma32(a1, b1, acc[1][1]);
  }

#pragma unroll
  for (int ti = 0; ti < 2; ++ti)
#pragma unroll
    for (int tj = 0; tj < 2; ++tj)
#pragma unroll
      for (int r = 0; r < 16; ++r) {
        int row = row0 + ti * 32 + (r & 3) + 8 * (r >> 2) + 4 * (lane >> 5);
        int col = col0 + tj * 32 + lm;
        C[(size_t)row * Nn + col] = f2b(acc[ti][tj][r]);
      }
}

// GEMM for layer 2: A[N,256] bf16 (aggh), Bt = W23t [256][256].
// by==0 -> cols 0..127 = mu (+ fused fragment-major bf16 zf), by==1 -> logvar.
__global__ __launch_bounds__(256) void gemm_mlv(
    const unsigned short* __restrict__ A, const unsigned short* __restrict__ Bt,
    float* __restrict__ mu, float* __restrict__ logvar,
    unsigned short* __restrict__ zf) {
  __shared__ unsigned short ltb[128][132];  // bf16 staging, 33.8 KB; stride
                                            // 264B == 2 banks mod 32 (free)
  int wave = threadIdx.x >> 6, lane = threadIdx.x & 63;
  int wr = wave >> 1, wc = wave & 1;
  int row0 = blockIdx.x * 128 + wr * 64;
  int colg0 = blockIdx.y * 128 + wc * 64;   // global col (B row)
  int lm = lane & 31, lk = (lane >> 5) * 8;
  const int K = HD1;

  f32x16 acc[2][2] = {};
  const unsigned short* a0p = A + (size_t)(row0 + lm) * K + lk;
  const unsigned short* a1p = a0p + (size_t)32 * K;
  const unsigned short* b0p = Bt + (size_t)(colg0 + lm) * K + lk;
  const unsigned short* b1p = b0p + (size_t)32 * K;

#pragma unroll 4
  for (int k0 = 0; k0 < K; k0 += 16) {
    bf16x8 a0 = ldb8(a0p + k0), a1 = ldb8(a1p + k0);
    bf16x8 b0 = ldb8(b0p + k0), b1 = ldb8(b1p + k0);
    acc[0][0] = mfma32(a0, b0, acc[0][0]);
    acc[0][1] = mfma32(a0, b1, acc[0][1]);
    acc[1][0] = mfma32(a1, b0, acc[1][0]);
    acc[1][1] = mfma32(a1, b1, acc[1][1]);
  }

  float* Cout = (blockIdx.y == 0) ? mu : logvar;
  bool do_zf = (zf != nullptr) && (blockIdx.y == 0);
#pragma unroll
  for (int ti = 0; ti < 2; ++ti)
#pragma unroll
    for (int tj = 0; tj < 2; ++tj)
#pragma unroll
      for (int r = 0; r < 16; ++r) {
        int rl = wr * 64 + ti * 32 + (r & 3) + 8 * (r >> 2) + 4 * (lane >> 5);
        int cl = wc * 64 + tj * 32 + lm;
        float vv = acc[ti][tj][r];
        Cout[(size_t)(blockIdx.x * 128 + rl) * HD2 + cl] = vv;
        if (do_zf) ltb[rl][cl] = f2b(vv);
      }

  if (do_zf) {
    __syncthreads();
    // emit fragment-major zf chunks for rows [bx*128, bx*128+128):
    // chunk t = (R*8 + C)*64 + ln ; elem j = Z[R*32+(ln&31)][C*16+(ln>>5)*8+j]
    int tid = threadIdx.x;
    for (int q = tid; q < 2048; q += 256) {
      int Rl = q >> 9;                 // 0..3
      int Cc = (q >> 6) & 7;           // 0..7
      int ln = q & 63;
      int rl = Rl * 32 + (ln & 31);
      int c0 = Cc * 16 + (ln >> 5) * 8;
      bf16x8 ch;
#pragma unroll
      for (int j = 0; j < 8; ++j) ch[j] = (short)ltb[rl][c0 + j];
      size_t tg = ((size_t)(blockIdx.x * 4 + Rl) * 8 + Cc) * 64 + ln;
      ((bf16x8*)zf)[tg] = ch;
    }
  }
}

// ---------------- SpMM (CSR gather, wave-per-node, bf16 rows 512B) ----------------
// out[i,:] = bf16( maybe_relu( sum_e val[e]*dense[dst[e],:] ) ), D = 256 bf16

template <int RELU>
__global__ __launch_bounds__(256) void k_spmm_b(
    const int* __restrict__ off, const int* __restrict__ dstp,
    const float* __restrict__ valp, const unsigned short* __restrict__ dense,
    unsigned short* __restrict__ outb) {
  int node = blockIdx.x * 4 + (threadIdx.x >> 6);
  int lane = threadIdx.x & 63;
  int l31 = lane & 31;
  int e0 = off[node];
  int e1 = (node == NN - 1) ? EE : off[node + 1];
  const ushort4* dp = (const ushort4*)dense;   // row = 64 ushort4 (512B)
  float a0 = 0.f, a1 = 0.f, a2 = 0.f, a3 = 0.f;
  int eb = e0;
  for (; eb + 32 <= e1; eb += 32) {
    int dd = dstp[eb + l31];
    float vv = valp[eb + l31];
#pragma unroll
    for (int j = 0; j < 32; ++j) {
      int dj = __shfl(dd, j);
      float vj = __shfl(vv, j);
      ushort4 r = dp[(size_t)dj * 64 + lane];
      a0 = fmaf(vj, b2f(r.x), a0);
      a1 = fmaf(vj, b2f(r.y), a1);
      a2 = fmaf(vj, b2f(r.z), a2);
      a3 = fmaf(vj, b2f(r.w), a3);
    }
  }
  int rem = e1 - eb;
  if (rem > 0) {
    int dd = 0; float vv = 0.f;
    if (l31 < rem) { dd = dstp[eb + l31]; vv = valp[eb + l31]; }
    for (int j = 0; j < rem; ++j) {
      int dj = __shfl(dd, j);
      float vj = __shfl(vv, j);
      ushort4 r = dp[(size_t)dj * 64 + lane];
      a0 = fmaf(vj, b2f(r.x), a0);
      a1 = fmaf(vj, b2f(r.y), a1);
      a2 = fmaf(vj, b2f(r.z), a2);
      a3 = fmaf(vj, b2f(r.w), a3);
    }
  }
  if (RELU) {
    a0 = fmaxf(a0, 0.f); a1 = fmaxf(a1, 0.f);
    a2 = fmaxf(a2, 0.f); a3 = fmaxf(a3, 0.f);
  }
  ushort4 ob;
  ob.x = f2b(a0); ob.y = f2b(a1); ob.z = f2b(a2); ob.w = f2b(a3);
  ((ushort4*)outb)[(size_t)node * 64 + lane] = ob;
}

// ---------------- Decoder: out = sigmoid(Z * Z^T) ----------------

// fragment-major zf variant, 128x256 tile, 512 threads (8 waves = 2x4)
__global__ __launch_bounds__(512) void k_decoder_z(const unsigned short* __restrict__ zf,
                                                   float* __restrict__ out) {
  int wave = threadIdx.x >> 6, lane = threadIdx.x & 63;
  int wr = wave >> 2, wc = wave & 3;
  int row0 = blockIdx.x * 128 + wr * 64;
  int col0 = blockIdx.y * 256 + wc * 64;
  int lm = lane & 31;
  int aR = row0 >> 5;
  int bR = col0 >> 5;
  const unsigned short* ap = zf + ((size_t)aR * 8 * 64 + lane) * 8;
  const unsigned short* bp = zf + ((size_t)bR * 8 * 64 + lane) * 8;

  f32x16 acc[2][2] = {};
#pragma unroll
  for (int C = 0; C < 8; ++C) {
    bf16x8 a0 = ldb8(ap + C * 512);
    bf16x8 a1 = ldb8(ap + 4096 + C * 512);
    bf16x8 b0 = ldb8(bp + C * 512);
    bf16x8 b1 = ldb8(bp + 4096 + C * 512);
    acc[0][0] = mfma32(a0, b0, acc[0][0]);
    acc[0][1] = mfma32(a0, b1, acc[0][1]);
    acc[1][0] = mfma32(a1, b0, acc[1][0]);
    acc[1][1] = mfma32(a1, b1, acc[1][1]);
  }

#pragma unroll
  for (int ti = 0; ti < 2; ++ti)
#pragma unroll
    for (int tj = 0; tj < 2; ++tj)
#pragma unroll
      for (int r = 0; r < 16; ++r) {
        int row = row0 + ti * 32 + (r & 3) + 8 * (r >> 2) + 4 * (lane >> 5);
        int col = col0 + tj * 32 + lm;
        float s = sigmoid_fast(acc[ti][tj][r]);
        __builtin_nontemporal_store(s, &out[(size_t)row * NN + col]);
      }
}

// fp32-Z fallback when ws is too small for zf
__global__ __launch_bounds__(256) void k_decoder(const float* __restrict__ Zf,
                                                 float* __restrict__ out) {
  int wave = threadIdx.x >> 6, lane = threadIdx.x & 63;
  int wr = wave >> 1, wc = wave & 1;
  int row0 = blockIdx.x * 128 + wr * 64;
  int col0 = blockIdx.y * 128 + wc * 64;
  int lm = lane & 31, lk = (lane >> 5) * 8;

  f32x16 acc[2][2] = {};
  const float* a0p = Zf + (size_t)(row0 + lm) * HD2 + lk;
  const float* a1p = a0p + (size_t)32 * HD2;
  const float* b0p = Zf + (size_t)(col0 + lm) * HD2 + lk;
  const float* b1p = b0p + (size_t)32 * HD2;

#pragma unroll
  for (int k0 = 0; k0 < HD2; k0 += 16) {
    bf16x8 a0 = ldf8(a0p + k0), a1 = ldf8(a1p + k0);
    bf16x8 b0 = ldf8(b0p + k0), b1 = ldf8(b1p + k0);
    acc[0][0] = mfma32(a0, b0, acc[0][0]);
    acc[0][1] = mfma32(a0, b1, acc[0][1]);
    acc[1][0] = mfma32(a1, b0, acc[1][0]);
    acc[1][1] = mfma32(a1, b1, acc[1][1]);
  }

#pragma unroll
  for (int ti = 0; ti < 2; ++ti)
#pragma unroll
    for (int tj = 0; tj < 2; ++tj)
#pragma unroll
      for (int r = 0; r < 16; ++r) {
        int row = row0 + ti * 32 + (r & 3) + 8 * (r >> 2) + 4 * (lane >> 5);
        int col = col0 + tj * 32 + lm;
        float s = sigmoid_fast(acc[ti][tj][r]);
        __builtin_nontemporal_store(s, &out[(size_t)row * NN + col]);
      }
}

// ---------------- launch ----------------

extern "C" void kernel_launch(void* const* d_in, const int* in_sizes, int n_in,
                              void* d_out, int out_size, void* d_ws, size_t ws_size,
                              hipStream_t stream) {
  const float* x  = (const float*)d_in[0];
  const int*   src = (const int*)d_in[1];
  const int*   dst = (const int*)d_in[2];
  const float* ev  = (const float*)d_in[3];
  const float* W1  = (const float*)d_in[4];
  const float* W2  = (const float*)d_in[5];
  const float* W3  = (const float*)d_in[6];
  float* out = (float*)d_out;
  float* mu     = out + (size_t)NN * NN;
  float* logvar = mu + (size_t)NN * HD2;

  // Scratch lives inside out[0 : NN*NN] (604 MB; we need ~40 MB). Every
  // scratch byte is dead before the decoder overwrites the region.
  char* p = (char*)d_out;
  auto alloc = [&](size_t bytes) {
    char* r = p;
    p += (bytes + 255) & ~(size_t)255;
    return r;
  };
  unsigned short* xb    = (unsigned short*)alloc((size_t)NN * FF * 2);
  unsigned short* W1t   = (unsigned short*)alloc((size_t)HD1 * FF * 2);
  unsigned short* W23t  = (unsigned short*)alloc((size_t)2 * HD2 * HD1 * 2);
  unsigned short* sup1b = (unsigned short*)alloc((size_t)NN * HD1 * 2);
  unsigned short* h1b   = (unsigned short*)alloc((size_t)NN * HD1 * 2);
  unsigned short* aggh  = (unsigned short*)alloc((size_t)NN * HD1 * 2);
  int* deg  = (int*)alloc(NN * 4);
  int* off  = (int*)alloc(NN * 4);
  int* cur  = (int*)alloc(NN * 4);
  int*   dstp = (int*)alloc((size_t)EE * 4);
  float* valp = (float*)alloc((size_t)EE * 4);

  // fragment-major bf16 Z in d_ws (3.15 MB); must NOT live inside
  // out[0:NN*NN] (decoder overwrites that region while blocks still read Z).
  const size_t zf_bytes = (size_t)NN * HD2 * 2;
  bool use_zf = (d_ws != nullptr) && (ws_size >= zf_bytes + 256);
  unsigned short* zf = use_zf ? (unsigned short*)d_ws : nullptr;

  // CSR build on src (permuting dst/val into CSR order) + fused prep
  hipMemsetAsync(deg, 0, NN * 4, stream);
  {
    int prep_total = PREP_NX + PREP_NW1 + 2 * PREP_NW23;
    int nb = HIST_NB + (prep_total + 255) / 256;
    k_hist_prep<<<nb, 256, 0, stream>>>(src, deg, x, xb, W1, W1t, W2, W3, W23t);
  }
  k_scan<<<1, 1024, 0, stream>>>(deg, off, cur);
  k_fill<<<EE / 256, 256, 0, stream>>>(src, dst, ev, cur, dstp, valp);

  // encoder layer 1: sup1b = bf16(x @ W1) ; h1b = bf16(relu(spmm(sup1b)))
  gemm_btb<FF><<<dim3(NN / 128, HD1 / 128), 256, 0, stream>>>(xb, W1t, sup1b, HD1);
  k_spmm_b<1><<<NN / 4, 256, 0, stream>>>(off, dstp, valp, sup1b, h1b);

  // encoder layer 2 (SpMM-first; spmm commutes with @W):
  // aggh = bf16(spmm(h1b)) ; [mu|logvar] = aggh @ [W2|W3] (+ fused zf emit)
  k_spmm_b<0><<<NN / 4, 256, 0, stream>>>(off, dstp, valp, h1b, aggh);
  gemm_mlv<<<dim3(NN / 128, 2), 256, 0, stream>>>(aggh, W23t, mu, logvar, zf);

  // decoder: out[0 : NN*NN] = sigmoid(z z^T), z = mu (eval mode)
  if (use_zf) {
    k_decoder_z<<<dim3(NN / 128, NN / 256), 512, 0, stream>>>(zf, out);
  } else {
    k_decoder<<<dim3(NN / 128, NN / 128), 256, 0, stream>>>(mu, out);
  }
}